// Round 1
// baseline (7131.710 us; speedup 1.0000x reference)
//
#include <hip/hip_runtime.h>
#include <hip/hip_bf16.h>

// LSTM: B=1024, T=512, I=64, H=256, O=1
// gates = x_t @ W_ih^T + b_ih + h @ W_hh^T + b_hh ; PyTorch gate order i,f,g,o
// Strategy: 64 WGs x 512 threads. WG owns 16 batch rows for all T steps.
// Wave w owns hidden cols [32w,32w+32): computes gate cols {g*256+32w..} for g=0..3,
// so nonlinearity + c update are wave-local. h exchanged via swizzled bf16 LDS.
// W_ih bf16 persistent in registers; W_hh bf16 streamed from L2 each step.

typedef float f32x4 __attribute__((ext_vector_type(4)));
typedef short s16x8 __attribute__((ext_vector_type(8)));

#define BB 1024
#define TT 512
#define II 64
#define HH 256
#define GG 1024  // 4*H

__device__ __forceinline__ ushort f2bf(float f) {
  unsigned u = __builtin_bit_cast(unsigned, f);
  u = (u + 0x7FFFu + ((u >> 16) & 1u)) >> 16;  // RNE
  return (ushort)u;
}

__device__ __forceinline__ float sigm(float x) {
  return 1.0f / (1.0f + __expf(-x));
}
// overflow-safe tanh: e in (0,1], saturates to +-1 correctly
__device__ __forceinline__ float tanh_s(float x) {
  float e = __expf(-2.0f * fabsf(x));
  float t = (1.0f - e) / (1.0f + e);
  return copysignf(t, x);
}

__global__ void cvt_weights(const float* __restrict__ wih,
                            const float* __restrict__ whh,
                            ushort* __restrict__ ws) {
  int i = blockIdx.x * 256 + threadIdx.x;
  if (i < GG * II) {
    ws[i] = f2bf(wih[i]);
  } else {
    int j = i - GG * II;
    if (j < GG * HH) ws[GG * II + j] = f2bf(whh[j]);
  }
}

template <bool BF>
__device__ __forceinline__ s16x8 load_bfrag(const void* base, int off) {
  if constexpr (BF) {
    return *(const s16x8*)((const ushort*)base + off);
  } else {
    const float* p = (const float*)base + off;
    f32x4 a = *(const f32x4*)p;
    f32x4 b = *(const f32x4*)(p + 4);
    s16x8 r;
    r[0] = (short)f2bf(a[0]); r[1] = (short)f2bf(a[1]);
    r[2] = (short)f2bf(a[2]); r[3] = (short)f2bf(a[3]);
    r[4] = (short)f2bf(b[0]); r[5] = (short)f2bf(b[1]);
    r[6] = (short)f2bf(b[2]); r[7] = (short)f2bf(b[3]);
    return r;
  }
}

template <bool WSBF>
__global__ __launch_bounds__(512, 2) void lstm_main(
    const float* __restrict__ x,      // [B,T,I]
    const float* __restrict__ wih_f,  // [4H,I]
    const float* __restrict__ whh_f,  // [4H,H]
    const float* __restrict__ b_ih,   // [4H]
    const float* __restrict__ b_hh,   // [4H]
    const float* __restrict__ w_out,  // [1,H]
    const float* __restrict__ b_out,  // [1]
    const ushort* __restrict__ wsb,   // bf16: [0,65536) W_ih, [65536,..) W_hh
    float* __restrict__ out)          // [B]
{
  __shared__ ushort h_lds[16 * 256];  // bf16 h, XOR-swizzled
  __shared__ float hf[16][256];       // final-step fp32 h

  const int tid  = threadIdx.x;
  const int wv   = tid >> 6;
  const int l    = tid & 63;
  const int lrow = l & 15;          // A row / B col within 16x16 tile
  const int lk8  = (l >> 4) << 3;   // k offset base for A/B frags
  const int crow = (l >> 4) << 2;   // C row base (+reg idx)
  const int ccol = l & 15;          // C col
  const int b0 = blockIdx.x << 4;   // batch base
  const int jw = wv << 5;           // hidden col base for this wave

  // zero h state
  {
    s16x8 z = {};
    *(s16x8*)&h_lds[tid * 8] = z;   // 512*8 = 4096 = 16*256
  }

  const void* wih_base = WSBF ? (const void*)wsb : (const void*)wih_f;
  const void* whh_base = WSBF ? (const void*)(wsb + GG * II) : (const void*)whh_f;

  // persistent W_ih fragments: [gate][ntile][ktile]
  s16x8 wih_frag[4][2][2];
#pragma unroll
  for (int g = 0; g < 4; ++g)
#pragma unroll
    for (int nt = 0; nt < 2; ++nt)
#pragma unroll
      for (int kt = 0; kt < 2; ++kt) {
        int jrow = g * 256 + jw + nt * 16 + lrow;
        wih_frag[g][nt][kt] = load_bfrag<WSBF>(wih_base, jrow * II + kt * 32 + lk8);
      }

  // bias sums (depend on C col only)
  float bs[4][2];
#pragma unroll
  for (int g = 0; g < 4; ++g)
#pragma unroll
    for (int nt = 0; nt < 2; ++nt) {
      int c = g * 256 + jw + nt * 16 + ccol;
      bs[g][nt] = b_ih[c] + b_hh[c];
    }

  float cst[2][4] = {};  // c state: [ntile][reg]

  __syncthreads();

  for (int t = 0; t < TT; ++t) {
    // x_t A-fragments (fp32 -> bf16)
    s16x8 xf[2];
    {
      const float* xp = x + ((size_t)(b0 + lrow) * TT + t) * II + lk8;
#pragma unroll
      for (int kt = 0; kt < 2; ++kt) {
        f32x4 a = *(const f32x4*)(xp + kt * 32);
        f32x4 b = *(const f32x4*)(xp + kt * 32 + 4);
        s16x8 r;
        r[0] = (short)f2bf(a[0]); r[1] = (short)f2bf(a[1]);
        r[2] = (short)f2bf(a[2]); r[3] = (short)f2bf(a[3]);
        r[4] = (short)f2bf(b[0]); r[5] = (short)f2bf(b[1]);
        r[6] = (short)f2bf(b[2]); r[7] = (short)f2bf(b[3]);
        xf[kt] = r;
      }
    }
    // h A-fragments from LDS (swizzled)
    s16x8 hfr[8];
#pragma unroll
    for (int kt = 0; kt < 8; ++kt) {
      int byte = lrow * 512 + (kt * 32 + lk8) * 2;
      byte ^= (lrow & 7) << 4;
      hfr[kt] = *(const s16x8*)((const char*)h_lds + byte);
    }

    f32x4 acc[4][2];
#pragma unroll
    for (int g = 0; g < 4; ++g)
#pragma unroll
      for (int nt = 0; nt < 2; ++nt) {
        f32x4 a;
        a[0] = a[1] = a[2] = a[3] = bs[g][nt];
        // stream W_hh B-fragments (bf16 from L2)
        s16x8 bw[8];
        int jrow = g * 256 + jw + nt * 16 + lrow;
#pragma unroll
        for (int kt = 0; kt < 8; ++kt)
          bw[kt] = load_bfrag<WSBF>(whh_base, jrow * HH + kt * 32 + lk8);
        a = __builtin_amdgcn_mfma_f32_16x16x32_bf16(xf[0], wih_frag[g][nt][0], a, 0, 0, 0);
        a = __builtin_amdgcn_mfma_f32_16x16x32_bf16(xf[1], wih_frag[g][nt][1], a, 0, 0, 0);
#pragma unroll
        for (int kt = 0; kt < 8; ++kt)
          a = __builtin_amdgcn_mfma_f32_16x16x32_bf16(hfr[kt], bw[kt], a, 0, 0, 0);
        acc[g][nt] = a;
      }

    __syncthreads();  // all waves finished reading h_lds

    // nonlinearity + state update; write h_new
#pragma unroll
    for (int nt = 0; nt < 2; ++nt)
#pragma unroll
      for (int r = 0; r < 4; ++r) {
        float gi = sigm(acc[0][nt][r]);
        float gf = sigm(acc[1][nt][r]);
        float gg = tanh_s(acc[2][nt][r]);
        float go = sigm(acc[3][nt][r]);
        float cn = gf * cst[nt][r] + gi * gg;
        cst[nt][r] = cn;
        float hn = go * tanh_s(cn);
        int row = crow + r;
        int col = jw + nt * 16 + ccol;
        int byte = (row * 512 + col * 2) ^ ((row & 7) << 4);
        *(ushort*)((char*)h_lds + byte) = f2bf(hn);
        if (t == TT - 1) hf[row][col] = hn;
      }

    __syncthreads();
  }

  // epilogue: out[b] = h_last . W_out + b_out   (fp32)
#pragma unroll
  for (int rr = 0; rr < 2; ++rr) {
    int row = wv * 2 + rr;
    float s = 0.f;
#pragma unroll
    for (int m = 0; m < 4; ++m)
      s += hf[row][l + 64 * m] * w_out[l + 64 * m];
#pragma unroll
    for (int off = 32; off >= 1; off >>= 1)
      s += __shfl_xor(s, off);
    if (l == 0) out[b0 + row] = s + b_out[0];
  }
}

extern "C" void kernel_launch(void* const* d_in, const int* in_sizes, int n_in,
                              void* d_out, int out_size, void* d_ws, size_t ws_size,
                              hipStream_t stream) {
  const float* x     = (const float*)d_in[0];
  const float* wih   = (const float*)d_in[1];
  const float* whh   = (const float*)d_in[2];
  const float* b_ih  = (const float*)d_in[3];
  const float* b_hh  = (const float*)d_in[4];
  const float* w_out = (const float*)d_in[5];
  const float* b_out = (const float*)d_in[6];
  float* out = (float*)d_out;

  const size_t ws_needed = (size_t)(GG * II + GG * HH) * sizeof(ushort);  // 640 KB
  if (ws_size >= ws_needed) {
    ushort* wsb = (ushort*)d_ws;
    int n = GG * II + GG * HH;
    cvt_weights<<<(n + 255) / 256, 256, 0, stream>>>(wih, whh, wsb);
    lstm_main<true><<<BB / 16, 512, 0, stream>>>(x, wih, whh, b_ih, b_hh, w_out,
                                                 b_out, wsb, out);
  } else {
    lstm_main<false><<<BB / 16, 512, 0, stream>>>(x, wih, whh, b_ih, b_hh, w_out,
                                                  b_out, nullptr, out);
  }
}